// Round 1
// baseline (1374.363 us; speedup 1.0000x reference)
//
#include <hip/hip_runtime.h>
#include <math.h>

#define Bc 2
#define Hh 32
#define Ww 32
#define Cc 384
#define NHc 12
#define NGc 6
#define CGc 64
#define HCc 32
#define GHc 2
#define HIDc 1536
#define Lc 1024
#define NSc 1024
#define BGc 12

__device__ __forceinline__ float gelu_f(float v) {
    return 0.5f * v * (1.f + erff(v * 0.70710678118654752440f));
}

// ---------------- LayerNorm over C=384, one row per 128-thread block ----
__global__ __launch_bounds__(128) void ln_kernel(
    const float* __restrict__ x, const float* __restrict__ w,
    const float* __restrict__ b, float* __restrict__ out)
{
    __shared__ float l1[2], l2[2];
    int row = blockIdx.x;
    int t = threadIdx.x;
    const float* xr = x + (size_t)row * Cc;
    float v0 = xr[t], v1 = xr[t + 128], v2 = xr[t + 256];
    float s = v0 + v1 + v2;
    #pragma unroll
    for (int o = 32; o; o >>= 1) s += __shfl_down(s, o);
    if ((t & 63) == 0) l1[t >> 6] = s;
    __syncthreads();
    float mu = (l1[0] + l1[1]) * (1.f / Cc);
    float d0 = v0 - mu, d1 = v1 - mu, d2 = v2 - mu;
    float q = d0 * d0 + d1 * d1 + d2 * d2;
    #pragma unroll
    for (int o = 32; o; o >>= 1) q += __shfl_down(q, o);
    if ((t & 63) == 0) l2[t >> 6] = q;
    __syncthreads();
    float rstd = rsqrtf((l2[0] + l2[1]) * (1.f / Cc) + 1e-5f);
    float* orow = out + (size_t)row * Cc;
    orow[t]       = d0 * rstd * w[t]       + b[t];
    orow[t + 128] = d1 * rstd * w[t + 128] + b[t + 128];
    orow[t + 256] = d2 * rstd * w[t + 256] + b[t + 256];
}

// ---------------- Tiled fp32 GEMM: out = W(J,K) x A (+bias, epilogue) ----
// A_KN:   A layout (K,N) if true else (N,K)
// OUT_NJ: out layout (N,J) if true else (J,N)
// EPI:    0 none, 1 gelu, 2 residual add (res has same layout/stride as out)
template<bool A_KN, bool OUT_NJ, int EPI>
__global__ __launch_bounds__(256) void gemm_kernel(
    const float* __restrict__ A, const float* __restrict__ Wt,
    const float* __restrict__ bias, const float* __restrict__ res,
    float* __restrict__ out, int N, int J, int K,
    int strideA, int strideO)
{
    __shared__ float As[32][33];   // As[k][n]
    __shared__ float Ws[32][33];   // Ws[k][j]
    int n0 = blockIdx.x * 32, j0 = blockIdx.y * 32;
    const float* Ab = A + (size_t)blockIdx.z * strideA;
    float* Ob = out + (size_t)blockIdx.z * strideO;
    const float* Rb = res + (size_t)blockIdx.z * strideO;
    int tid = threadIdx.x;
    int tx = tid & 31, ty = tid >> 5;
    float acc[4] = {0.f, 0.f, 0.f, 0.f};
    for (int k0 = 0; k0 < K; k0 += 32) {
        #pragma unroll
        for (int i = 0; i < 4; i++) {
            int rr = ty + i * 8;
            if (A_KN) As[rr][tx] = Ab[(size_t)(k0 + rr) * N + n0 + tx];
            else      As[tx][rr] = Ab[(size_t)(n0 + rr) * K + k0 + tx];
            Ws[tx][rr] = Wt[(size_t)(j0 + rr) * K + k0 + tx];
        }
        __syncthreads();
        #pragma unroll
        for (int kk = 0; kk < 32; kk++) {
            if (OUT_NJ) {
                float w = Ws[kk][tx];
                #pragma unroll
                for (int i = 0; i < 4; i++) acc[i] += As[kk][ty + i * 8] * w;
            } else {
                float a = As[kk][tx];
                #pragma unroll
                for (int i = 0; i < 4; i++) acc[i] += a * Ws[kk][ty + i * 8];
            }
        }
        __syncthreads();
    }
    #pragma unroll
    for (int i = 0; i < 4; i++) {
        int j, n;
        if (OUT_NJ) { j = j0 + tx; n = n0 + ty + i * 8; }
        else        { j = j0 + ty + i * 8; n = n0 + tx; }
        float v = acc[i] + bias[j];
        if (EPI == 1) v = gelu_f(v);
        size_t oi = OUT_NJ ? (size_t)n * J + j : (size_t)j * N + n;
        if (EPI == 2) v += Rb[oi];
        Ob[oi] = v;
    }
}

// ---------------- Depthwise 7x7 conv (per group-channel) -----------------
// q layout (B, C, L); out o_dw layout (BG, CG, L)
__global__ __launch_bounds__(256) void dwconv_kernel(
    const float* __restrict__ q, const float* __restrict__ wdw,
    const float* __restrict__ bdw, float* __restrict__ o_dw)
{
    int cg = blockIdx.x, bg = blockIdx.y;
    int b = bg / NGc, g = bg % NGc;
    __shared__ float wk_s[49];
    if (threadIdx.x < 49) wk_s[threadIdx.x] = wdw[cg * 49 + threadIdx.x];
    __syncthreads();
    const float* qp = q + (size_t)(b * Cc + g * CGc + cg) * Lc;
    float bias = bdw[cg];
    #pragma unroll
    for (int i = 0; i < 4; i++) {
        int hw = threadIdx.x + i * 256;
        int y = hw >> 5, xx = hw & 31;
        float acc = bias;
        #pragma unroll
        for (int ky = 0; ky < 7; ky++) {
            int yy = y + ky - 3;
            if (yy < 0 || yy > 31) continue;
            #pragma unroll
            for (int kx = 0; kx < 7; kx++) {
                int x2 = xx + kx - 3;
                if (x2 < 0 || x2 > 31) continue;
                acc += qp[yy * 32 + x2] * wk_s[ky * 7 + kx];
            }
        }
        o_dw[(size_t)(bg * CGc + cg) * Lc + hw] = acc;
    }
}

// ---------------- LN(CG) + GELU + pointwise -> tanh -> pos ---------------
// one wave (64 threads = CG) per (bg, hw)
__global__ __launch_bounds__(64) void offset_kernel(
    const float* __restrict__ o_dw, const float* __restrict__ lnw,
    const float* __restrict__ lnb, const float* __restrict__ pw,
    float* __restrict__ pos)
{
    int hw = blockIdx.x, bg = blockIdx.y;
    int cg = threadIdx.x;
    float v = o_dw[(size_t)(bg * CGc + cg) * Lc + hw];
    float s = v;
    #pragma unroll
    for (int o = 32; o; o >>= 1) s += __shfl_down(s, o);
    s = __shfl(s, 0, 64);
    float mu = s * (1.f / CGc);
    float d = v - mu;
    float q2 = d * d;
    #pragma unroll
    for (int o = 32; o; o >>= 1) q2 += __shfl_down(q2, o);
    q2 = __shfl(q2, 0, 64);
    float rstd = rsqrtf(q2 * (1.f / CGc) + 1e-5f);
    float t = d * rstd * lnw[cg] + lnb[cg];
    float gl = gelu_f(t);
    float sy = gl * pw[cg];
    float sx = gl * pw[CGc + cg];
    #pragma unroll
    for (int o = 32; o; o >>= 1) {
        sy += __shfl_down(sy, o);
        sx += __shfl_down(sx, o);
    }
    if (threadIdx.x == 0) {
        float offy = tanhf(sy) * 0.0625f;   // tanh * (1/32) * 2
        float offx = tanhf(sx) * 0.0625f;
        int y = hw >> 5, xx = hw & 31;
        pos[((size_t)bg * Lc + hw) * 2 + 0] = offy + ((y + 0.5f) * (2.f / Hh) - 1.f);
        pos[((size_t)bg * Lc + hw) * 2 + 1] = offx + ((xx + 0.5f) * (2.f / Ww) - 1.f);
    }
}

// ---------------- bilinear grid-sample of xn at pos -> xs (B,C,NS) -------
__global__ __launch_bounds__(256) void sample_kernel(
    const float* __restrict__ xn, const float* __restrict__ pos,
    float* __restrict__ xs)
{
    int n = blockIdx.x * 256 + threadIdx.x;
    int cg = blockIdx.y, bg = blockIdx.z;
    int b = bg / NGc, g = bg % NGc;
    float py = pos[((size_t)bg * NSc + n) * 2 + 0];
    float px = pos[((size_t)bg * NSc + n) * 2 + 1];
    float fx = (px + 1.f) * 0.5f * 31.f;
    float fy = (py + 1.f) * 0.5f * 31.f;
    float x0f = floorf(fx), y0f = floorf(fy);
    int x0 = (int)x0f, y0 = (int)y0f;
    float wx1 = fx - x0f, wy1 = fy - y0f;
    float wx0 = 1.f - wx1, wy0 = 1.f - wy1;
    const float* base = xn + (size_t)(b * Lc) * Cc + (g * CGc + cg);
    float acc = 0.f;
    if (y0 >= 0 && y0 <= 31) {
        if (x0 >= 0 && x0 <= 31) acc += base[(size_t)(y0 * 32 + x0) * Cc] * wx0 * wy0;
        if (x0 + 1 >= 0 && x0 + 1 <= 31) acc += base[(size_t)(y0 * 32 + x0 + 1) * Cc] * wx1 * wy0;
    }
    if (y0 + 1 >= 0 && y0 + 1 <= 31) {
        if (x0 >= 0 && x0 <= 31) acc += base[(size_t)((y0 + 1) * 32 + x0) * Cc] * wx0 * wy1;
        if (x0 + 1 >= 0 && x0 + 1 <= 31) acc += base[(size_t)((y0 + 1) * 32 + x0 + 1) * Cc] * wx1 * wy1;
    }
    xs[(size_t)(b * Cc + g * CGc + cg) * NSc + n] = acc;
}

// ---------------- fused attention row: one block per (b, h, m) -----------
__global__ __launch_bounds__(256) void attn_kernel(
    const float* __restrict__ q, const float* __restrict__ kb,
    const float* __restrict__ vb, const float* __restrict__ pos,
    const float* __restrict__ rpe, float* __restrict__ attno)
{
    __shared__ float qv[HCc];
    __shared__ float p[NSc + NSc / 32];   // padded: idx n + (n>>5)
    __shared__ float redm[4], reds[4];
    __shared__ float red2[256];
    int m = blockIdx.x, h = blockIdx.y, b = blockIdx.z;
    int g = h >> 1;            // GH = 2
    int bg = b * NGc + g;
    int tid = threadIdx.x;
    if (tid < HCc) qv[tid] = q[(size_t)(b * Cc + h * HCc + tid) * Lc + m];
    __syncthreads();
    int my = m >> 5, mx = m & 31;
    float qgy = (my + 0.5f) * (2.f / Hh) - 1.f;
    float qgx = (mx + 0.5f) * (2.f / Ww) - 1.f;
    const float* tb = rpe + (size_t)h * 3969;   // 63*63
    const float* kp0 = kb + (size_t)(b * Cc + h * HCc) * NSc;
    float sv[4];
    float lmax = -3.4e38f;
    #pragma unroll
    for (int i = 0; i < 4; i++) {
        int n = tid + i * 256;
        float acc = 0.f;
        const float* kp = kp0 + n;
        #pragma unroll
        for (int c = 0; c < HCc; c++) acc += qv[c] * kp[(size_t)c * NSc];
        acc *= 0.17677669529663688f;   // 32^-0.5
        float py = pos[((size_t)bg * NSc + n) * 2 + 0];
        float px = pos[((size_t)bg * NSc + n) * 2 + 1];
        float fy = ((qgy - py) * 0.5f + 1.f) * 31.f;   // (d+1)*0.5*62
        float fx = ((qgx - px) * 0.5f + 1.f) * 31.f;
        float y0f = floorf(fy), x0f = floorf(fx);
        int iy = (int)y0f, ix = (int)x0f;
        float wy1 = fy - y0f, wx1 = fx - x0f;
        float wy0 = 1.f - wy1, wx0 = 1.f - wx1;
        float bias = 0.f;
        if (iy >= 0 && iy <= 62) {
            if (ix >= 0 && ix <= 62) bias += tb[iy * 63 + ix] * wy0 * wx0;
            if (ix + 1 >= 0 && ix + 1 <= 62) bias += tb[iy * 63 + ix + 1] * wy0 * wx1;
        }
        if (iy + 1 >= 0 && iy + 1 <= 62) {
            if (ix >= 0 && ix <= 62) bias += tb[(iy + 1) * 63 + ix] * wy1 * wx0;
            if (ix + 1 >= 0 && ix + 1 <= 62) bias += tb[(iy + 1) * 63 + ix + 1] * wy1 * wx1;
        }
        acc += bias;
        sv[i] = acc;
        lmax = fmaxf(lmax, acc);
    }
    #pragma unroll
    for (int o = 32; o; o >>= 1) lmax = fmaxf(lmax, __shfl_down(lmax, o));
    if ((tid & 63) == 0) redm[tid >> 6] = lmax;
    __syncthreads();
    float bmax = fmaxf(fmaxf(redm[0], redm[1]), fmaxf(redm[2], redm[3]));
    float ls = 0.f;
    #pragma unroll
    for (int i = 0; i < 4; i++) {
        int n = tid + i * 256;
        float e = expf(sv[i] - bmax);
        p[n + (n >> 5)] = e;
        ls += e;
    }
    #pragma unroll
    for (int o = 32; o; o >>= 1) ls += __shfl_down(ls, o);
    if ((tid & 63) == 0) reds[tid >> 6] = ls;
    __syncthreads();
    float inv = 1.f / (reds[0] + reds[1] + reds[2] + reds[3]);
    // PV: thread (c, seg): c = tid>>3 in [0,32), seg = tid&7, 128 n per seg
    int c = tid >> 3, seg = tid & 7;
    const float* vp = vb + (size_t)(b * Cc + h * HCc + c) * NSc + seg * 128;
    int pbase = seg * 132;   // seg*128 + seg*4 (padding)
    float part = 0.f;
    for (int ii = 0; ii < 128; ii++)
        part += p[pbase + ii + (ii >> 5)] * vp[ii];
    red2[tid] = part;
    __syncthreads();
    if (seg < 4) red2[tid] += red2[tid + 4];
    __syncthreads();
    if (seg < 2) red2[tid] += red2[tid + 2];
    __syncthreads();
    if (seg == 0)
        attno[(size_t)(b * Cc + h * HCc + c) * Lc + m] =
            (red2[tid] + red2[tid + 1]) * inv;
}

extern "C" void kernel_launch(void* const* d_in, const int* in_sizes, int n_in,
                              void* d_out, int out_size, void* d_ws, size_t ws_size,
                              hipStream_t stream)
{
    const float* x    = (const float*)d_in[0];
    const float* n1w  = (const float*)d_in[1];
    const float* n1b  = (const float*)d_in[2];
    const float* wq   = (const float*)d_in[3];
    const float* bq   = (const float*)d_in[4];
    const float* wk   = (const float*)d_in[5];
    const float* bk   = (const float*)d_in[6];
    const float* wv   = (const float*)d_in[7];
    const float* bv   = (const float*)d_in[8];
    const float* wo   = (const float*)d_in[9];
    const float* bo   = (const float*)d_in[10];
    const float* dw_w = (const float*)d_in[11];
    const float* dw_b = (const float*)d_in[12];
    const float* lnw  = (const float*)d_in[13];
    const float* lnb  = (const float*)d_in[14];
    const float* pw_w = (const float*)d_in[15];
    const float* rpe  = (const float*)d_in[16];
    const float* n2w  = (const float*)d_in[17];
    const float* n2b  = (const float*)d_in[18];
    const float* fc1w = (const float*)d_in[19];
    const float* fc1b = (const float*)d_in[20];
    const float* fc2w = (const float*)d_in[21];
    const float* fc2b = (const float*)d_in[22];
    float* out = (float*)d_out;

    float* ws    = (float*)d_ws;
    float* xn    = ws;                 // 786432  (B,L,C)   dead after sample
    float* qb    = ws + 786432;        // 786432  (B,C,L)   dead after attn
    float* odw   = ws + 1572864;       // 786432  (BG,CG,L) dead after offset
    float* posb  = ws + 2359296;       // 24576   (BG,NS,2) dead after attn
    float* xs    = ws + 2383872;       // 786432  (B,C,NS)  dead after k/v proj
    float* kbuf  = ws + 3170304;       // 786432  (B,C,NS)
    float* vbuf  = ws + 3956736;       // 786432  (B,C,NS)
    float* attno = ws + 4743168;       // 786432  (B,C,L)
    float* x2    = ws + 5529600;       // 786432  (B,L,C)
    float* xln2  = ws + 6316032;       // 786432  (B,L,C)
    float* h1    = ws;                 // 3145728 (B*L,HID) aliases xn..xs (dead)

    // 1. LN1
    ln_kernel<<<Bc * Lc, 128, 0, stream>>>(x, n1w, n1b, xn);
    // 2. q projection -> (B, C, L)
    gemm_kernel<false, false, 0><<<dim3(Lc / 32, Cc / 32, Bc), 256, 0, stream>>>(
        xn, wq, bq, qb, qb, Lc, Cc, Cc, Lc * Cc, Cc * Lc);
    // 3. depthwise 7x7
    dwconv_kernel<<<dim3(CGc, BGc), 256, 0, stream>>>(qb, dw_w, dw_b, odw);
    // 4. offset head -> pos
    offset_kernel<<<dim3(Lc, BGc), 64, 0, stream>>>(odw, lnw, lnb, pw_w, posb);
    // 5. grid-sample xn -> xs
    sample_kernel<<<dim3(NSc / 256, CGc, BGc), 256, 0, stream>>>(xn, posb, xs);
    // 6/7. k, v projections -> (B, C, NS)
    gemm_kernel<true, false, 0><<<dim3(NSc / 32, Cc / 32, Bc), 256, 0, stream>>>(
        xs, wk, bk, kbuf, kbuf, NSc, Cc, Cc, Cc * NSc, Cc * NSc);
    gemm_kernel<true, false, 0><<<dim3(NSc / 32, Cc / 32, Bc), 256, 0, stream>>>(
        xs, wv, bv, vbuf, vbuf, NSc, Cc, Cc, Cc * NSc, Cc * NSc);
    // 8. fused attention (scores + rpe bias + softmax + PV)
    attn_kernel<<<dim3(Lc, NHc, Bc), 256, 0, stream>>>(qb, kbuf, vbuf, posb, rpe, attno);
    // 9. out projection + residual -> x2 (B,L,C)
    gemm_kernel<true, true, 2><<<dim3(Lc / 32, Cc / 32, Bc), 256, 0, stream>>>(
        attno, wo, bo, x, x2, Lc, Cc, Cc, Cc * Lc, Lc * Cc);
    // 10. LN2
    ln_kernel<<<Bc * Lc, 128, 0, stream>>>(x2, n2w, n2b, xln2);
    // 11. fc1 + GELU -> h1 (B*L, HID)
    gemm_kernel<false, true, 1><<<dim3(Bc * Lc / 32, HIDc / 32, 1), 256, 0, stream>>>(
        xln2, fc1w, fc1b, h1, h1, Bc * Lc, HIDc, Cc, 0, 0);
    // 12. fc2 + residual -> out
    gemm_kernel<false, true, 2><<<dim3(Bc * Lc / 32, Cc / 32, 1), 256, 0, stream>>>(
        h1, fc2w, fc2b, x2, out, Bc * Lc, Cc, HIDc, 0, 0);
}

// Round 2
// 713.287 us; speedup vs baseline: 1.9268x; 1.9268x over previous
//
#include <hip/hip_runtime.h>
#include <math.h>

#define Bc 2
#define Hh 32
#define Ww 32
#define Cc 384
#define NHc 12
#define NGc 6
#define CGc 64
#define HCc 32
#define GHc 2
#define HIDc 1536
#define Lc 1024
#define NSc 1024
#define BGc 12

__device__ __forceinline__ float gelu_f(float v) {
    return 0.5f * v * (1.f + erff(v * 0.70710678118654752440f));
}

// ---------------- LayerNorm over C=384, one row per 128-thread block ----
__global__ __launch_bounds__(128) void ln_kernel(
    const float* __restrict__ x, const float* __restrict__ w,
    const float* __restrict__ b, float* __restrict__ out)
{
    __shared__ float l1[2], l2[2];
    int row = blockIdx.x;
    int t = threadIdx.x;
    const float* xr = x + (size_t)row * Cc;
    float v0 = xr[t], v1 = xr[t + 128], v2 = xr[t + 256];
    float s = v0 + v1 + v2;
    #pragma unroll
    for (int o = 32; o; o >>= 1) s += __shfl_down(s, o);
    if ((t & 63) == 0) l1[t >> 6] = s;
    __syncthreads();
    float mu = (l1[0] + l1[1]) * (1.f / Cc);
    float d0 = v0 - mu, d1 = v1 - mu, d2 = v2 - mu;
    float q = d0 * d0 + d1 * d1 + d2 * d2;
    #pragma unroll
    for (int o = 32; o; o >>= 1) q += __shfl_down(q, o);
    if ((t & 63) == 0) l2[t >> 6] = q;
    __syncthreads();
    float rstd = rsqrtf((l2[0] + l2[1]) * (1.f / Cc) + 1e-5f);
    float* orow = out + (size_t)row * Cc;
    orow[t]       = d0 * rstd * w[t]       + b[t];
    orow[t + 128] = d1 * rstd * w[t + 128] + b[t + 128];
    orow[t + 256] = d2 * rstd * w[t + 256] + b[t + 256];
}

// ---------------- 64x64-tile fp32 GEMM: out = W(J,K) x A -----------------
// A_KN:   A layout (K,N) if true else (N,K)
// OUT_NJ: out layout (N,J) if true else (J,N)
// EPI:    0 none, 1 gelu, 2 residual add
template<bool A_KN, bool OUT_NJ, int EPI>
__global__ __launch_bounds__(256) void gemm_kernel(
    const float* __restrict__ A, const float* __restrict__ Wt,
    const float* __restrict__ bias, const float* __restrict__ res,
    float* __restrict__ out, int N, int J, int K,
    int strideA, int strideO)
{
    __shared__ float As[16][68];   // As[k][n]
    __shared__ float Ws[16][68];   // Ws[k][j]
    int n0 = blockIdx.x * 64, j0 = blockIdx.y * 64;
    const float* Ab = A + (size_t)blockIdx.z * strideA;
    float* Ob = out + (size_t)blockIdx.z * strideO;
    const float* Rb = res + (size_t)blockIdx.z * strideO;
    int tid = threadIdx.x;
    int mg = tid & 15, jg = tid >> 4;
    float acc[4][4] = {};
    for (int k0 = 0; k0 < K; k0 += 16) {
        if (A_KN) {
            int nn = tid & 63, r0 = tid >> 6;
            #pragma unroll
            for (int i = 0; i < 4; i++)
                As[r0 + i * 4][nn] = Ab[(size_t)(k0 + r0 + i * 4) * N + n0 + nn];
        } else {
            int kk2 = tid & 15, nb = tid >> 4;
            #pragma unroll
            for (int i = 0; i < 4; i++)
                As[kk2][nb + i * 16] = Ab[(size_t)(n0 + nb + i * 16) * K + k0 + kk2];
        }
        {
            int kk2 = tid & 15, jb = tid >> 4;
            #pragma unroll
            for (int i = 0; i < 4; i++)
                Ws[kk2][jb + i * 16] = Wt[(size_t)(j0 + jb + i * 16) * K + k0 + kk2];
        }
        __syncthreads();
        #pragma unroll
        for (int kk = 0; kk < 16; kk++) {
            float4 a4 = *(const float4*)&As[kk][mg * 4];
            float4 w4 = *(const float4*)&Ws[kk][jg * 4];
            float av[4] = {a4.x, a4.y, a4.z, a4.w};
            float wv[4] = {w4.x, w4.y, w4.z, w4.w};
            #pragma unroll
            for (int i = 0; i < 4; i++)
                #pragma unroll
                for (int j = 0; j < 4; j++)
                    acc[i][j] += av[i] * wv[j];
        }
        __syncthreads();
    }
    if (OUT_NJ) {
        float4 b4 = *(const float4*)&bias[j0 + jg * 4];
        float bv[4] = {b4.x, b4.y, b4.z, b4.w};
        #pragma unroll
        for (int i = 0; i < 4; i++) {
            int n = n0 + mg * 4 + i;
            float4 v;
            float* vp = (float*)&v;
            #pragma unroll
            for (int j = 0; j < 4; j++) {
                float t2 = acc[i][j] + bv[j];
                if (EPI == 1) t2 = gelu_f(t2);
                vp[j] = t2;
            }
            size_t oi = (size_t)n * J + j0 + jg * 4;
            if (EPI == 2) {
                float4 r4 = *(const float4*)&Rb[oi];
                v.x += r4.x; v.y += r4.y; v.z += r4.z; v.w += r4.w;
            }
            *(float4*)&Ob[oi] = v;
        }
    } else {
        #pragma unroll
        for (int j = 0; j < 4; j++) {
            int jj = j0 + jg * 4 + j;
            float bv = bias[jj];
            float4 v;
            float* vp = (float*)&v;
            #pragma unroll
            for (int i = 0; i < 4; i++) {
                float t2 = acc[i][j] + bv;
                if (EPI == 1) t2 = gelu_f(t2);
                vp[i] = t2;
            }
            size_t oi = (size_t)jj * N + n0 + mg * 4;
            if (EPI == 2) {
                float4 r4 = *(const float4*)&Rb[oi];
                v.x += r4.x; v.y += r4.y; v.z += r4.z; v.w += r4.w;
            }
            *(float4*)&Ob[oi] = v;
        }
    }
}

// ---------------- Depthwise 7x7 conv (per group-channel), LDS-staged -----
__global__ __launch_bounds__(256) void dwconv_kernel(
    const float* __restrict__ q, const float* __restrict__ wdw,
    const float* __restrict__ bdw, float* __restrict__ o_dw)
{
    int cg = blockIdx.x, bg = blockIdx.y;
    int b = bg / NGc, g = bg % NGc;
    __shared__ float wk_s[49];
    __shared__ float img[1024];
    const float* qp = q + (size_t)(b * Cc + g * CGc + cg) * Lc;
    if (threadIdx.x < 49) wk_s[threadIdx.x] = wdw[cg * 49 + threadIdx.x];
    #pragma unroll
    for (int i = 0; i < 4; i++) img[threadIdx.x + i * 256] = qp[threadIdx.x + i * 256];
    __syncthreads();
    float bias = bdw[cg];
    #pragma unroll
    for (int i = 0; i < 4; i++) {
        int hw = threadIdx.x + i * 256;
        int y = hw >> 5, xx = hw & 31;
        float acc = bias;
        #pragma unroll
        for (int ky = 0; ky < 7; ky++) {
            int yy = y + ky - 3;
            if (yy < 0 || yy > 31) continue;
            #pragma unroll
            for (int kx = 0; kx < 7; kx++) {
                int x2 = xx + kx - 3;
                if (x2 < 0 || x2 > 31) continue;
                acc += img[yy * 32 + x2] * wk_s[ky * 7 + kx];
            }
        }
        o_dw[(size_t)(bg * CGc + cg) * Lc + hw] = acc;
    }
}

// ---------------- LN(CG) + GELU + pointwise -> tanh -> pos ---------------
__global__ __launch_bounds__(64) void offset_kernel(
    const float* __restrict__ o_dw, const float* __restrict__ lnw,
    const float* __restrict__ lnb, const float* __restrict__ pw,
    float* __restrict__ pos)
{
    int hw = blockIdx.x, bg = blockIdx.y;
    int cg = threadIdx.x;
    float v = o_dw[(size_t)(bg * CGc + cg) * Lc + hw];
    float s = v;
    #pragma unroll
    for (int o = 32; o; o >>= 1) s += __shfl_down(s, o);
    s = __shfl(s, 0, 64);
    float mu = s * (1.f / CGc);
    float d = v - mu;
    float q2 = d * d;
    #pragma unroll
    for (int o = 32; o; o >>= 1) q2 += __shfl_down(q2, o);
    q2 = __shfl(q2, 0, 64);
    float rstd = rsqrtf(q2 * (1.f / CGc) + 1e-5f);
    float t = d * rstd * lnw[cg] + lnb[cg];
    float gl = gelu_f(t);
    float sy = gl * pw[cg];
    float sx = gl * pw[CGc + cg];
    #pragma unroll
    for (int o = 32; o; o >>= 1) {
        sy += __shfl_down(sy, o);
        sx += __shfl_down(sx, o);
    }
    if (threadIdx.x == 0) {
        float offy = tanhf(sy) * 0.0625f;
        float offx = tanhf(sx) * 0.0625f;
        int y = hw >> 5, xx = hw & 31;
        pos[((size_t)bg * Lc + hw) * 2 + 0] = offy + ((y + 0.5f) * (2.f / Hh) - 1.f);
        pos[((size_t)bg * Lc + hw) * 2 + 1] = offx + ((xx + 0.5f) * (2.f / Ww) - 1.f);
    }
}

// ---------------- bilinear grid-sample of xn at pos -> xs (B,NS,C) -------
// lanes over channels: coalesced reads (xn row-contig) and writes
__global__ __launch_bounds__(256) void sample_kernel(
    const float* __restrict__ xn, const float* __restrict__ pos,
    float* __restrict__ xs)
{
    int cg = threadIdx.x & 63;
    int nl = threadIdx.x >> 6;
    int n = blockIdx.x * 4 + nl;
    int bg = blockIdx.y;
    int b = bg / NGc, g = bg % NGc;
    float py = pos[((size_t)bg * NSc + n) * 2 + 0];
    float px = pos[((size_t)bg * NSc + n) * 2 + 1];
    float fx = (px + 1.f) * 0.5f * 31.f;
    float fy = (py + 1.f) * 0.5f * 31.f;
    float x0f = floorf(fx), y0f = floorf(fy);
    int x0 = (int)x0f, y0 = (int)y0f;
    float wx1 = fx - x0f, wy1 = fy - y0f;
    float wx0 = 1.f - wx1, wy0 = 1.f - wy1;
    const float* base = xn + (size_t)(b * Lc) * Cc + g * CGc + cg;
    float acc = 0.f;
    if (y0 >= 0 && y0 <= 31) {
        if (x0 >= 0 && x0 <= 31) acc += base[(size_t)(y0 * 32 + x0) * Cc] * wx0 * wy0;
        if (x0 + 1 >= 0 && x0 + 1 <= 31) acc += base[(size_t)(y0 * 32 + x0 + 1) * Cc] * wx1 * wy0;
    }
    if (y0 + 1 >= 0 && y0 + 1 <= 31) {
        if (x0 >= 0 && x0 <= 31) acc += base[(size_t)((y0 + 1) * 32 + x0) * Cc] * wx0 * wy1;
        if (x0 + 1 >= 0 && x0 + 1 <= 31) acc += base[(size_t)((y0 + 1) * 32 + x0 + 1) * Cc] * wx1 * wy1;
    }
    xs[((size_t)(b * NSc) + n) * Cc + g * CGc + cg] = acc;
}

// ---------------- flash-style attention: block = (b, h, 64-m tile) -------
__global__ __launch_bounds__(256) void attn_kernel(
    const float* __restrict__ q, const float* __restrict__ kb,
    const float* __restrict__ vb, const float* __restrict__ pos,
    const float* __restrict__ rpe, float* __restrict__ attno)
{
    __shared__ float q_s[32][68];    // [c][m]
    __shared__ float k_s[32][68];    // [c][n]
    __shared__ float v_t[64][34];    // [n][c]
    __shared__ float p_s[64][68];    // [n][m]: raw scores, then P
    __shared__ float pos_s[64][2];
    __shared__ float mx_s[64], al_s[64], l_s[64];
    __shared__ float red_s[4][64];

    int m0 = blockIdx.x * 64;
    int h = blockIdx.y, b = blockIdx.z;
    int bg = b * NGc + (h >> 1);     // GH = 2
    int tid = threadIdx.x;

    const float* qbase = q + (size_t)(b * Cc + h * HCc) * Lc + m0;
    {
        int mm = tid & 63, c0 = tid >> 6;
        #pragma unroll
        for (int i = 0; i < 8; i++)
            q_s[c0 + i * 4][mm] = qbase[(size_t)(c0 + i * 4) * Lc + mm];
    }
    if (tid < 64) { mx_s[tid] = -3.0e38f; l_s[tid] = 0.f; }

    int mg = tid & 15, ng = tid >> 4;
    float qgy[4], qgx[4];
    #pragma unroll
    for (int i = 0; i < 4; i++) {
        int m = m0 + mg * 4 + i;
        qgy[i] = ((m >> 5) + 0.5f) * (2.f / 32.f) - 1.f;
        qgx[i] = ((m & 31) + 0.5f) * (2.f / 32.f) - 1.f;
    }
    const float* tb = rpe + (size_t)h * 3969;
    const float* kbase = kb + (size_t)(b * Cc + h * HCc) * NSc;
    const float* vbase = vb + (size_t)(b * Cc + h * HCc) * NSc;
    const float* posb = pos + (size_t)bg * NSc * 2;

    float O[4][2] = {};
    int pm = tid & 15, pc = tid >> 4;

    for (int n0 = 0; n0 < NSc; n0 += 64) {
        __syncthreads();   // prior tile's p_s/k_s/v_t fully consumed
        {
            int nn = tid & 63, c0 = tid >> 6;
            #pragma unroll
            for (int i = 0; i < 8; i++) {
                int c = c0 + i * 4;
                k_s[c][nn] = kbase[(size_t)c * NSc + n0 + nn];
                v_t[nn][c] = vbase[(size_t)c * NSc + n0 + nn];
            }
        }
        if (tid < 128) ((float*)pos_s)[tid] = posb[n0 * 2 + tid];
        __syncthreads();

        float acc[4][4] = {};
        #pragma unroll
        for (int c = 0; c < 32; c++) {
            float4 q4 = *(const float4*)&q_s[c][mg * 4];
            float4 k4 = *(const float4*)&k_s[c][ng * 4];
            float qv[4] = {q4.x, q4.y, q4.z, q4.w};
            float kv[4] = {k4.x, k4.y, k4.z, k4.w};
            #pragma unroll
            for (int i = 0; i < 4; i++)
                #pragma unroll
                for (int j = 0; j < 4; j++)
                    acc[i][j] += qv[i] * kv[j];
        }
        #pragma unroll
        for (int ni = 0; ni < 4; ni++) {
            int n = ng * 4 + ni;
            float py = pos_s[n][0], px = pos_s[n][1];
            float4 col;
            float* colp = (float*)&col;
            #pragma unroll
            for (int mi = 0; mi < 4; mi++) {
                float fy = ((qgy[mi] - py) * 0.5f + 1.f) * 31.f;
                float fx = ((qgx[mi] - px) * 0.5f + 1.f) * 31.f;
                float y0f = floorf(fy), x0f = floorf(fx);
                int iy = (int)y0f, ix = (int)x0f;
                float wy1 = fy - y0f, wx1 = fx - x0f;
                float wy0 = 1.f - wy1, wx0 = 1.f - wx1;
                float bias = 0.f;
                if (iy >= 0 && iy <= 62) {
                    const float* r = tb + iy * 63;
                    if (ix >= 0 && ix <= 62) bias += r[ix] * wy0 * wx0;
                    if (ix + 1 >= 0 && ix + 1 <= 62) bias += r[ix + 1] * wy0 * wx1;
                }
                if (iy + 1 >= 0 && iy + 1 <= 62) {
                    const float* r = tb + (iy + 1) * 63;
                    if (ix >= 0 && ix <= 62) bias += r[ix] * wy1 * wx0;
                    if (ix + 1 >= 0 && ix + 1 <= 62) bias += r[ix + 1] * wy1 * wx1;
                }
                colp[mi] = acc[mi][ni] * 0.17677669529663688f + bias;
            }
            *(float4*)&p_s[n][mg * 4] = col;
        }
        __syncthreads();
        {   // partial row max (4 threads per m-row)
            int m = tid & 63, hf = tid >> 6;
            float mxv = -3.0e38f;
            #pragma unroll
            for (int k2 = 0; k2 < 16; k2++)
                mxv = fmaxf(mxv, p_s[hf * 16 + k2][m]);
            red_s[hf][m] = mxv;
        }
        __syncthreads();
        if (tid < 64) {
            float nm = fmaxf(fmaxf(red_s[0][tid], red_s[1][tid]),
                             fmaxf(red_s[2][tid], red_s[3][tid]));
            nm = fmaxf(nm, mx_s[tid]);
            al_s[tid] = expf(mx_s[tid] - nm);
            mx_s[tid] = nm;
        }
        __syncthreads();
        #pragma unroll
        for (int i = 0; i < 4; i++) {   // rescale O
            float al = al_s[pm * 4 + i];
            O[i][0] *= al; O[i][1] *= al;
        }
        {   // exp in place + partial row sum
            int m = tid & 63, hf = tid >> 6;
            float mxm = mx_s[m];
            float sum = 0.f;
            #pragma unroll
            for (int k2 = 0; k2 < 16; k2++) {
                float e = expf(p_s[hf * 16 + k2][m] - mxm);
                p_s[hf * 16 + k2][m] = e;
                sum += e;
            }
            red_s[hf][m] = sum;
        }
        __syncthreads();
        if (tid < 64)
            l_s[tid] = l_s[tid] * al_s[tid]
                     + red_s[0][tid] + red_s[1][tid] + red_s[2][tid] + red_s[3][tid];
        // PV accumulate
        #pragma unroll 4
        for (int n = 0; n < 64; n++) {
            float4 p4 = *(const float4*)&p_s[n][pm * 4];
            float2 v2 = *(const float2*)&v_t[n][pc * 2];
            O[0][0] += p4.x * v2.x; O[0][1] += p4.x * v2.y;
            O[1][0] += p4.y * v2.x; O[1][1] += p4.y * v2.y;
            O[2][0] += p4.z * v2.x; O[2][1] += p4.z * v2.y;
            O[3][0] += p4.w * v2.x; O[3][1] += p4.w * v2.y;
        }
    }
    __syncthreads();
    #pragma unroll
    for (int i = 0; i < 4; i++) {
        int m = m0 + pm * 4 + i;
        float inv = 1.f / l_s[pm * 4 + i];
        #pragma unroll
        for (int j = 0; j < 2; j++) {
            int c = pc * 2 + j;
            attno[(size_t)(b * Cc + h * HCc + c) * Lc + m] = O[i][j] * inv;
        }
    }
}

extern "C" void kernel_launch(void* const* d_in, const int* in_sizes, int n_in,
                              void* d_out, int out_size, void* d_ws, size_t ws_size,
                              hipStream_t stream)
{
    const float* x    = (const float*)d_in[0];
    const float* n1w  = (const float*)d_in[1];
    const float* n1b  = (const float*)d_in[2];
    const float* wq   = (const float*)d_in[3];
    const float* bq   = (const float*)d_in[4];
    const float* wk   = (const float*)d_in[5];
    const float* bk   = (const float*)d_in[6];
    const float* wv   = (const float*)d_in[7];
    const float* bv   = (const float*)d_in[8];
    const float* wo   = (const float*)d_in[9];
    const float* bo   = (const float*)d_in[10];
    const float* dw_w = (const float*)d_in[11];
    const float* dw_b = (const float*)d_in[12];
    const float* lnw  = (const float*)d_in[13];
    const float* lnb  = (const float*)d_in[14];
    const float* pw_w = (const float*)d_in[15];
    const float* rpe  = (const float*)d_in[16];
    const float* n2w  = (const float*)d_in[17];
    const float* n2b  = (const float*)d_in[18];
    const float* fc1w = (const float*)d_in[19];
    const float* fc1b = (const float*)d_in[20];
    const float* fc2w = (const float*)d_in[21];
    const float* fc2b = (const float*)d_in[22];
    float* out = (float*)d_out;

    float* ws    = (float*)d_ws;
    float* xn    = ws;                 // 786432  (B,L,C)   dead after sample
    float* qb    = ws + 786432;        // 786432  (B,C,L)   dead after attn
    float* odw   = ws + 1572864;       // 786432  (BG,CG,L) dead after offset
    float* posb  = ws + 2359296;       // 24576   (BG,NS,2) dead after attn
    float* xs    = ws + 2383872;       // 786432  (B,NS,C)  dead after k/v proj
    float* kbuf  = ws + 3170304;       // 786432  (B,C,NS)
    float* vbuf  = ws + 3956736;       // 786432  (B,C,NS)
    float* attno = ws + 4743168;       // 786432  (B,C,L)
    float* x2    = ws + 5529600;       // 786432  (B,L,C)
    float* xln2  = ws + 6316032;       // 786432  (B,L,C)
    float* h1    = ws;                 // 3145728 (B*L,HID) aliases dead xn..xs

    // 1. LN1
    ln_kernel<<<Bc * Lc, 128, 0, stream>>>(x, n1w, n1b, xn);
    // 2. q projection -> (B, C, L)
    gemm_kernel<false, false, 0><<<dim3(Lc / 64, Cc / 64, Bc), 256, 0, stream>>>(
        xn, wq, bq, qb, qb, Lc, Cc, Cc, Lc * Cc, Cc * Lc);
    // 3. depthwise 7x7
    dwconv_kernel<<<dim3(CGc, BGc), 256, 0, stream>>>(qb, dw_w, dw_b, odw);
    // 4. offset head -> pos
    offset_kernel<<<dim3(Lc, BGc), 64, 0, stream>>>(odw, lnw, lnb, pw_w, posb);
    // 5. grid-sample xn -> xs (B, NS, C)
    sample_kernel<<<dim3(NSc / 4, BGc), 256, 0, stream>>>(xn, posb, xs);
    // 6/7. k, v projections -> (B, C, NS)
    gemm_kernel<false, false, 0><<<dim3(NSc / 64, Cc / 64, Bc), 256, 0, stream>>>(
        xs, wk, bk, kbuf, kbuf, NSc, Cc, Cc, NSc * Cc, Cc * NSc);
    gemm_kernel<false, false, 0><<<dim3(NSc / 64, Cc / 64, Bc), 256, 0, stream>>>(
        xs, wv, bv, vbuf, vbuf, NSc, Cc, Cc, NSc * Cc, Cc * NSc);
    // 8. flash attention (scores + rpe bias + online softmax + PV)
    attn_kernel<<<dim3(Lc / 64, NHc, Bc), 256, 0, stream>>>(qb, kbuf, vbuf, posb, rpe, attno);
    // 9. out projection + residual -> x2 (B,L,C)
    gemm_kernel<true, true, 2><<<dim3(Lc / 64, Cc / 64, Bc), 256, 0, stream>>>(
        attno, wo, bo, x, x2, Lc, Cc, Cc, Cc * Lc, Lc * Cc);
    // 10. LN2
    ln_kernel<<<Bc * Lc, 128, 0, stream>>>(x2, n2w, n2b, xln2);
    // 11. fc1 + GELU -> h1 (B*L, HID)
    gemm_kernel<false, true, 1><<<dim3(Bc * Lc / 64, HIDc / 64, 1), 256, 0, stream>>>(
        xln2, fc1w, fc1b, h1, h1, Bc * Lc, HIDc, Cc, 0, 0);
    // 12. fc2 + residual -> out
    gemm_kernel<false, true, 2><<<dim3(Bc * Lc / 64, Cc / 64, 1), 256, 0, stream>>>(
        h1, fc2w, fc2b, x2, out, Bc * Lc, Cc, HIDc, 0, 0);
}